// Round 9
// baseline (634.598 us; speedup 1.0000x reference)
//
#include <hip/hip_runtime.h>

// Problem constants (match reference)
#define N_USER  500000
#define N_GROUP 100000
#define N_EDGE  5000000
#define DIM     64

#define SCAN_BLOCK 256
#define SCAN_ELEMS 4096            // elements per scan block (16 per thread)
#define PER_THREAD (SCAN_ELEMS / SCAN_BLOCK)

// Multisplit coarse-bucket geometry
#define KD_SHIFT 7                                   // 128 group-keys / coarse bucket
#define KS_SHIFT 9                                   // 512 user-keys / coarse bucket
#define C_DST ((N_GROUP + (1 << KD_SHIFT) - 1) >> KD_SHIFT)   // 782
#define C_SRC ((N_USER  + (1 << KS_SHIFT) - 1) >> KS_SHIFT)   // 977
#define TILE_A 16384                                 // edges per pass-A block
#define GRID_A ((N_EDGE + TILE_A - 1) / TILE_A)      // 306
#define CVT_BLOCKS 1024
// LDS staging caps: mean + ~16 sigma
#define CAP_D 7680
#define CAP_S 6272
// count-matrix sizes (+1 scan-total slot)
#define MD_N (C_DST * GRID_A)
#define MS_N (C_SRC * GRID_A)

typedef unsigned int uint32;

__device__ inline unsigned short f2bf(float x) {
    uint32 b = __float_as_uint(x);
    uint32 r = (b + 0x7FFFu + ((b >> 16) & 1u)) >> 16;   // round-to-nearest-even
    return (unsigned short)r;
}
__device__ inline float ldt(const float* t, size_t i) { return t[i]; }
__device__ inline float ldt(const unsigned short* t, size_t i) {
    return __uint_as_float((uint32)t[i] << 16);
}

// ---------------------------------------------------------------------------
// Fused prep: blocks [0,GRID_A) build their per-block coarse histogram in LDS
// and STORE it into the [bucket][block] count matrices (no global atomics);
// blocks [GRID_A, GRID_A+CVT_BLOCKS) convert h_user -> bf16.
// ---------------------------------------------------------------------------
__global__ void prep_kernel(const int* __restrict__ src,
                            const int* __restrict__ dst,
                            int* __restrict__ mat_d,
                            int* __restrict__ mat_s,
                            const float* __restrict__ hin,
                            unsigned short* __restrict__ h16) {
    __shared__ int hd[C_DST], hs[C_SRC];
    int tid = threadIdx.x;
    int b = blockIdx.x;
    if (b < GRID_A) {
        long base = (long)b * TILE_A;
        for (int k = tid; k < C_DST; k += blockDim.x) hd[k] = 0;
        for (int k = tid; k < C_SRC; k += blockDim.x) hs[k] = 0;
        __syncthreads();
        for (int i = tid; i < TILE_A; i += blockDim.x) {
            long e = base + i;
            if (e >= N_EDGE) break;
            atomicAdd(&hd[dst[e] >> KD_SHIFT], 1);
            atomicAdd(&hs[src[e] >> KS_SHIFT], 1);
        }
        __syncthreads();
        for (int k = tid; k < C_DST; k += blockDim.x) mat_d[(size_t)k * GRID_A + b] = hd[k];
        for (int k = tid; k < C_SRC; k += blockDim.x) mat_s[(size_t)k * GRID_A + b] = hs[k];
    } else if (h16) {
        long n4 = (long)N_USER * DIM / 4;
        long stride = (long)CVT_BLOCKS * blockDim.x;
        for (long i = (long)(b - GRID_A) * blockDim.x + tid; i < n4; i += stride) {
            const float4 v = ((const float4*)hin)[i];
            ushort4 o;
            o.x = f2bf(v.x); o.y = f2bf(v.y); o.z = f2bf(v.z); o.w = f2bf(v.w);
            ((ushort4*)h16)[i] = o;
        }
    }
}

// ---------------------------------------------------------------------------
// Exclusive scan (3 stages). Used (in-place) on the count matrices and by the
// fallback tiers.
// ---------------------------------------------------------------------------
__global__ void scan1_kernel(const int* __restrict__ cnt,
                             int* __restrict__ off,
                             int* __restrict__ partial,
                             int n) {
    __shared__ int sh[SCAN_BLOCK];
    int tid = threadIdx.x;
    int tbase = blockIdx.x * SCAN_ELEMS + tid * PER_THREAD;
    int local[PER_THREAD];
    int sum = 0;
#pragma unroll
    for (int i = 0; i < PER_THREAD; ++i) {
        int idx = tbase + i;
        int v = (idx < n) ? cnt[idx] : 0;
        local[i] = sum;
        sum += v;
    }
    sh[tid] = sum;
    __syncthreads();
    for (int o = 1; o < SCAN_BLOCK; o <<= 1) {
        int t = (tid >= o) ? sh[tid - o] : 0;
        __syncthreads();
        sh[tid] += t;
        __syncthreads();
    }
    int texc = sh[tid] - sum;
    int blockTotal = sh[SCAN_BLOCK - 1];
#pragma unroll
    for (int i = 0; i < PER_THREAD; ++i) {
        int idx = tbase + i;
        if (idx < n) off[idx] = local[i] + texc;
    }
    if (tid == 0) partial[blockIdx.x] = blockTotal;
}

__global__ void scan2_kernel(int* __restrict__ partial, int nb,
                             int* __restrict__ off_end) {
    __shared__ int sh[SCAN_BLOCK];
    int tid = threadIdx.x;
    int v = (tid < nb) ? partial[tid] : 0;
    sh[tid] = v;
    __syncthreads();
    for (int o = 1; o < SCAN_BLOCK; o <<= 1) {
        int t = (tid >= o) ? sh[tid - o] : 0;
        __syncthreads();
        sh[tid] += t;
        __syncthreads();
    }
    if (tid < nb) partial[tid] = sh[tid] - v;
    if (tid == 0) *off_end = sh[SCAN_BLOCK - 1];
}

__global__ void scan3_kernel(int* __restrict__ off,
                             const int* __restrict__ partial, int n) {
    int base = blockIdx.x * SCAN_ELEMS;
    int add = partial[blockIdx.x];
    for (int i = threadIdx.x; i < SCAN_ELEMS; i += blockDim.x) {
        int idx = base + i;
        if (idx < n) off[idx] += add;
    }
}

// ---------------------------------------------------------------------------
// Pass A: exact-offset placement. Each block loads its column of the scanned
// count matrices (absolute run bases), then places packed u32 (keylo<<20|val)
// with LDS cursor atomics only. One edge read; zero global atomics.
// ---------------------------------------------------------------------------
__global__ void passA(const int* __restrict__ src,
                      const int* __restrict__ dst,
                      const int* __restrict__ mat_d,
                      const int* __restrict__ mat_s,
                      uint32* __restrict__ coarse_dst,
                      uint32* __restrict__ coarse_src) {
    __shared__ int bd[C_DST], bs[C_SRC];
    int tid = threadIdx.x;
    int b = blockIdx.x;
    long base = (long)b * TILE_A;

    for (int c = tid; c < C_DST; c += blockDim.x) bd[c] = mat_d[(size_t)c * GRID_A + b];
    for (int c = tid; c < C_SRC; c += blockDim.x) bs[c] = mat_s[(size_t)c * GRID_A + b];
    __syncthreads();

    for (int i = tid; i < TILE_A; i += blockDim.x) {
        long e = base + i;
        if (e >= N_EDGE) break;
        int g = dst[e], u = src[e];
        int cd = g >> KD_SHIFT;
        int pd = atomicAdd(&bd[cd], 1);
        coarse_dst[pd] = ((uint32)(g & ((1 << KD_SHIFT) - 1)) << 20) | (uint32)u;
        int cs = u >> KS_SHIFT;
        int ps = atomicAdd(&bs[cs], 1);
        coarse_src[ps] = ((uint32)(u & ((1 << KS_SHIFT) - 1)) << 20) | (uint32)g;
    }
}

// ---------------------------------------------------------------------------
// Generic fused sort+gather (fwd; also bwd fallback when planes unavailable).
// beg/end come from the scanned count matrix at stride GRID_A.
// p0/p1: optional bf16 half-plane outputs [row][0:32) / [row][32:64).
// ---------------------------------------------------------------------------
template <int SHIFT, int CAP, int U, bool NT, typename T>
__global__ __launch_bounds__(512) void sortgather(
    const uint32* __restrict__ coarse,
    const int* __restrict__ mat,
    const T* __restrict__ table,
    float* __restrict__ out,
    unsigned short* __restrict__ p0,
    unsigned short* __restrict__ p1,
    int n) {
    const int NK = 1 << SHIFT;
    __shared__ int vals[CAP];
    __shared__ int hist[NK];
    __shared__ int cur[NK];
    int tid = threadIdx.x;
    int c = blockIdx.x;
    int lo_g = c << SHIFT;
    int beg = mat[(size_t)c * GRID_A];
    int end = mat[(size_t)(c + 1) * GRID_A];
    int cnt = end - beg;
    int stg = min(cnt, CAP);

    for (int k = tid; k < NK; k += 512) hist[k] = 0;
    __syncthreads();

    for (int i = tid; i < stg; i += 512) {
        atomicAdd(&hist[coarse[beg + i] >> 20], 1);
    }
    __syncthreads();

    for (int o = 1; o < NK; o <<= 1) {
        int t = (tid < NK && tid >= o) ? hist[tid - o] : 0;
        __syncthreads();
        if (tid < NK) hist[tid] += t;
        __syncthreads();
    }
    if (tid < NK) cur[tid] = (tid == 0) ? 0 : hist[tid - 1];
    __syncthreads();

    for (int i = tid; i < stg; i += 512) {
        uint32 kv = coarse[beg + i];
        int p = atomicAdd(&cur[kv >> 20], 1);
        vals[p] = (int)(kv & 0xFFFFFu);
    }
    __syncthreads();

    int wv = tid >> 6, lane = tid & 63;
    for (int r = wv; r < NK; r += 8) {
        int row = lo_g + r;
        if (row >= n) break;
        int lo = (r == 0) ? 0 : hist[r - 1];
        int hi = hist[r];
        float a[U];
#pragma unroll
        for (int j = 0; j < U; ++j) a[j] = 0.0f;
        int e = lo;
        for (; e + U <= hi; e += U) {
#pragma unroll
            for (int j = 0; j < U; ++j) {
                int s = vals[e + j];
                a[j] += ldt(table, (size_t)s * DIM + lane);
            }
        }
        for (; e < hi; ++e) {
            int s = vals[e];
            a[0] += ldt(table, (size_t)s * DIM + lane);
        }
        int deg = hi - lo;
        if (stg < cnt) {                 // overflow scan (rare)
            for (int i = beg + stg; i < end; ++i) {
                uint32 kv = coarse[i];
                if ((int)(kv >> 20) == r) {
                    a[0] += ldt(table, (size_t)(kv & 0xFFFFFu) * DIM + lane);
                    ++deg;
                }
            }
        }
        float acc = 0.0f;
#pragma unroll
        for (int j = 0; j < U; ++j) acc += a[j];
        float rv = acc / fmaxf((float)deg, 1.0f);
        size_t oidx = (size_t)row * DIM + lane;
        if (NT) __builtin_nontemporal_store(rv, &out[oidx]);
        else out[oidx] = rv;
        if (p0) {
            unsigned short bv = f2bf(rv);
            if (lane < 32) p0[(size_t)row * 32 + lane] = bv;
            else           p1[(size_t)row * 32 + (lane - 32)] = bv;
        }
    }
}

// ---------------------------------------------------------------------------
// Bwd sort+gather over bf16 half-planes: sorts once in LDS, then sweeps
// plane 0 for all rows, then plane 1 -> instantaneous table working set is
// 6.4 MB (vs 12.8), raising per-XCD L2 hit rate. Two edges per wave-step
// (lanes split 2x32); shfl_xor(32) folds the pair accumulators.
// ---------------------------------------------------------------------------
template <int SHIFT, int CAP>
__global__ __launch_bounds__(512) void sortgather_bwd(
    const uint32* __restrict__ coarse,
    const int* __restrict__ mat,
    const unsigned short* __restrict__ p0,
    const unsigned short* __restrict__ p1,
    float* __restrict__ out,
    int n) {
    const int NK = 1 << SHIFT;
    __shared__ int vals[CAP];
    __shared__ int hist[NK];
    __shared__ int cur[NK];
    int tid = threadIdx.x;
    int c = blockIdx.x;
    int lo_g = c << SHIFT;
    int beg = mat[(size_t)c * GRID_A];
    int end = mat[(size_t)(c + 1) * GRID_A];
    int cnt = end - beg;
    int stg = min(cnt, CAP);

    for (int k = tid; k < NK; k += 512) hist[k] = 0;
    __syncthreads();
    for (int i = tid; i < stg; i += 512) {
        atomicAdd(&hist[coarse[beg + i] >> 20], 1);
    }
    __syncthreads();
    for (int o = 1; o < NK; o <<= 1) {
        int t = (tid < NK && tid >= o) ? hist[tid - o] : 0;
        __syncthreads();
        if (tid < NK) hist[tid] += t;
        __syncthreads();
    }
    if (tid < NK) cur[tid] = (tid == 0) ? 0 : hist[tid - 1];
    __syncthreads();
    for (int i = tid; i < stg; i += 512) {
        uint32 kv = coarse[beg + i];
        int p = atomicAdd(&cur[kv >> 20], 1);
        vals[p] = (int)(kv & 0xFFFFFu);
    }
    __syncthreads();

    int wv = tid >> 6, lane = tid & 63;
    int sub = lane >> 5, d = lane & 31;
    for (int h = 0; h < 2; ++h) {
        const unsigned short* pl = h ? p1 : p0;
        for (int r = wv; r < NK; r += 8) {
            int row = lo_g + r;
            if (row >= n) break;
            int lo = (r == 0) ? 0 : hist[r - 1];
            int hi = hist[r];
            int deg = hi - lo;
            float a = 0.0f, b2 = 0.0f;
            int e = lo;
            for (; e + 4 <= hi; e += 4) {
                int s0 = vals[e + sub];
                int s1 = vals[e + 2 + sub];
                a  += ldt(pl, (size_t)s0 * 32 + d);
                b2 += ldt(pl, (size_t)s1 * 32 + d);
            }
            for (; e < hi; e += 2) {
                int ee = e + sub;
                float w = (ee < hi) ? 1.0f : 0.0f;
                int s = vals[ee < hi ? ee : hi - 1];
                a += w * ldt(pl, (size_t)s * 32 + d);
            }
            if (stg < cnt) {             // overflow scan (rare)
                for (int i = beg + stg; i < end; ++i) {
                    uint32 kv = coarse[i];
                    if ((int)(kv >> 20) == r) {
                        float w = (sub == 0) ? 1.0f : 0.0f;
                        a += w * ldt(pl, (size_t)(kv & 0xFFFFFu) * 32 + d);
                        ++deg;
                    }
                }
            }
            float s = a + b2;
            s += __shfl_xor(s, 32);
            float rv = s / fmaxf((float)deg, 1.0f);
            if (sub == 0)
                __builtin_nontemporal_store(rv, &out[(size_t)row * DIM + h * 32 + d]);
        }
    }
}

// ---------------------------------------------------------------------------
// Fallback-tier kernels (unchanged behavior).
// ---------------------------------------------------------------------------
__global__ void hist_kernel(const int* __restrict__ src,
                            const int* __restrict__ dst,
                            int* __restrict__ cnt_src,
                            int* __restrict__ cnt_dst) {
    int e = blockIdx.x * blockDim.x + threadIdx.x;
    if (e < N_EDGE) {
        atomicAdd(&cnt_src[src[e]], 1);
        atomicAdd(&cnt_dst[dst[e]], 1);
    }
}

__global__ void fill_both(const int* __restrict__ src,
                          const int* __restrict__ dst,
                          const int* __restrict__ off_src,
                          const int* __restrict__ off_dst,
                          int* __restrict__ cur_src,
                          int* __restrict__ cur_dst,
                          int* __restrict__ bucket_src,
                          int* __restrict__ bucket_dst) {
    int e = blockIdx.x * blockDim.x + threadIdx.x;
    if (e < N_EDGE) {
        int u = src[e];
        int g = dst[e];
        int p = atomicAdd(&cur_src[u], 1);
        bucket_src[off_src[u] + p] = g;
        int q = atomicAdd(&cur_dst[g], 1);
        bucket_dst[off_dst[g] + q] = u;
    }
}

__global__ void fill_one(const int* __restrict__ key,
                         const int* __restrict__ val,
                         const int* __restrict__ off,
                         int* __restrict__ cur,
                         int* __restrict__ bucket) {
    int e = blockIdx.x * blockDim.x + threadIdx.x;
    if (e < N_EDGE) {
        int k = key[e];
        int p = atomicAdd(&cur[k], 1);
        bucket[off[k] + p] = val[e];
    }
}

__global__ void cvt_bf16(const float* __restrict__ in,
                         unsigned short* __restrict__ out, long n4) {
    long i = (long)blockIdx.x * blockDim.x + threadIdx.x;
    if (i >= n4) return;
    const float4 v = ((const float4*)in)[i];
    ushort4 o;
    o.x = f2bf(v.x); o.y = f2bf(v.y); o.z = f2bf(v.z); o.w = f2bf(v.w);
    ((ushort4*)out)[i] = o;
}

// Gather (fallback tiers): one wave per row, window load + shfl broadcast.
template <int NROW, bool NT, int U, typename T>
__global__ void gather_kernel(const int* __restrict__ off,
                              const int* __restrict__ bucket,
                              const T* __restrict__ table,
                              float* __restrict__ out,
                              unsigned short* __restrict__ out16) {
    int wid = (blockIdx.x * blockDim.x + threadIdx.x) >> 6;
    int lane = threadIdx.x & 63;
    if (wid >= NROW) return;
    int beg = off[wid], end = off[wid + 1];

    float a[U];
#pragma unroll
    for (int j = 0; j < U; ++j) a[j] = 0.0f;

    for (int b = beg; b < end; b += 64) {
        int navail = min(64, end - b);
        int sv = bucket[b + (lane < navail ? lane : 0)];
        int k = 0;
        for (; k + U <= navail; k += U) {
#pragma unroll
            for (int j = 0; j < U; ++j) {
                int s = __shfl(sv, k + j);
                a[j] += ldt(table, (size_t)s * DIM + lane);
            }
        }
        if (k < navail) {
#pragma unroll
            for (int j = 0; j < U; ++j) {
                int kk = k + j;
                int s = __shfl(sv, kk < navail ? kk : navail - 1);
                float w = (kk < navail) ? 1.0f : 0.0f;
                a[j] += w * ldt(table, (size_t)s * DIM + lane);
            }
        }
    }
    float acc = 0.0f;
#pragma unroll
    for (int j = 0; j < U; ++j) acc += a[j];
    float inv = 1.0f / fmaxf((float)(end - beg), 1.0f);
    float r = acc * inv;
    if (NT) {
        __builtin_nontemporal_store(r, &out[(size_t)wid * DIM + lane]);
    } else {
        out[(size_t)wid * DIM + lane] = r;
    }
    if (out16) out16[(size_t)wid * DIM + lane] = f2bf(r);
}

// ===========================================================================
// Last-resort fallback (atomic path).
// ===========================================================================
__global__ void deg_kernel(const int* __restrict__ src,
                           const int* __restrict__ dst,
                           float* __restrict__ deg_src,
                           float* __restrict__ deg_dst) {
    int e = blockIdx.x * blockDim.x + threadIdx.x;
    if (e < N_EDGE) {
        unsafeAtomicAdd(&deg_src[src[e]], 1.0f);
        unsafeAtomicAdd(&deg_dst[dst[e]], 1.0f);
    }
}

__global__ void scatter_fwd(const int* __restrict__ src,
                            const int* __restrict__ dst,
                            const float* __restrict__ h_user,
                            float* __restrict__ rst) {
    long idx = (long)blockIdx.x * blockDim.x + threadIdx.x;
    if (idx >= (long)N_EDGE * DIM) return;
    int e = (int)(idx >> 6), d = (int)(idx & 63);
    unsafeAtomicAdd(&rst[(long)dst[e] * DIM + d], h_user[(long)src[e] * DIM + d]);
}

__global__ void norm_kernel(float* __restrict__ x,
                            const float* __restrict__ deg, long total) {
    long idx = (long)blockIdx.x * blockDim.x + threadIdx.x;
    if (idx >= total) return;
    float dg = fmaxf(deg[idx >> 6], 1.0f);
    x[idx] *= (1.0f / dg);
}

__global__ void scatter_bwd(const int* __restrict__ src,
                            const int* __restrict__ dst,
                            const float* __restrict__ rst,
                            float* __restrict__ bsrc) {
    long idx = (long)blockIdx.x * blockDim.x + threadIdx.x;
    if (idx >= (long)N_EDGE * DIM) return;
    int e = (int)(idx >> 6), d = (int)(idx & 63);
    unsafeAtomicAdd(&bsrc[(long)src[e] * DIM + d], rst[(long)dst[e] * DIM + d]);
}

extern "C" void kernel_launch(void* const* d_in, const int* in_sizes, int n_in,
                              void* d_out, int out_size, void* d_ws, size_t ws_size,
                              hipStream_t stream) {
    const float* h_user   = (const float*)d_in[0];
    const int*   edge_src = (const int*)d_in[2];
    const int*   edge_dst = (const int*)d_in[3];

    float* bsrc = (float*)d_out;                   // [N_USER, DIM]
    float* rst  = bsrc + (size_t)N_USER * DIM;     // [N_GROUP, DIM]

    const int BLK = 256;
    const int grid_e = (N_EDGE + BLK - 1) / BLK;

    // ---- scratch layout (header kept fallback-compatible) ---------------
    int* ws      = (int*)d_ws;
    int* cnt_dst = ws;                              // N_GROUP        (fallback only)
    int* off_dst = cnt_dst + N_GROUP;               // N_GROUP + 1
    int* cnt_src = off_dst + N_GROUP + 1;           // N_USER         (fallback only)
    int* off_src = cnt_src + N_USER;                // N_USER + 1
    int* cur_dst = off_src + N_USER + 1;            // N_GROUP        (fallback only)
    int* cur_src = cur_dst + N_GROUP;               // N_USER         (fallback only)
    int* partial = cur_src + N_USER;                // 256
    int* bucket_dst = partial + 256;                // N_EDGE (fallback only)
    int* bucket_src = bucket_dst + N_EDGE;          // N_EDGE (fallback only)
    unsigned short* r16 = (unsigned short*)(bucket_src + N_EDGE);  // N_GROUP*DIM (planes on ms path)
    unsigned short* h16 = r16 + (size_t)N_GROUP * DIM;             // N_USER*DIM
    unsigned short* rp0 = r16;                                     // plane 0 [g][32]
    unsigned short* rp1 = r16 + (size_t)N_GROUP * 32;              // plane 1 [g][32]
    // multisplit extras (8B-aligned tail)
    size_t tail = ((size_t)((char*)(h16 + (size_t)N_USER * DIM) - (char*)d_ws) + 7) & ~(size_t)7;
    int* mat_d = (int*)((char*)d_ws + tail);        // C_DST*GRID_A + 1
    int* mat_s = mat_d + MD_N + 1;                  // C_SRC*GRID_A + 1
    size_t tail2 = ((size_t)((char*)(mat_s + MS_N + 1) - (char*)d_ws) + 7) & ~(size_t)7;
    uint32* coarse_dst = (uint32*)((char*)d_ws + tail2);  // N_EDGE u32 (packed)
    uint32* coarse_src = coarse_dst + N_EDGE;             // N_EDGE u32 (packed)

    size_t need_csr1 = (size_t)((bucket_dst + N_EDGE) - ws) * sizeof(int);
    size_t need_csr2 = (size_t)((bucket_src + N_EDGE) - ws) * sizeof(int);
    size_t need_r16  = need_csr2 + (size_t)N_GROUP * DIM * 2;
    size_t need_full = need_r16 + (size_t)N_USER * DIM * 2;
    size_t need_ms   = (size_t)((char*)(coarse_src + N_EDGE) - (char*)d_ws);

    int nb_dst = (N_GROUP + SCAN_ELEMS - 1) / SCAN_ELEMS;
    int nb_src = (N_USER + SCAN_ELEMS - 1) / SCAN_ELEMS;

    if (ws_size >= need_ms) {
        // ---- multisplit + exact-offset + fused sortgather ----------------
        bool use_h16 = (ws_size >= need_full);
        bool use_r16 = (ws_size >= need_r16);

        int gridP = GRID_A + (use_h16 ? CVT_BLOCKS : 0);
        prep_kernel<<<gridP, BLK, 0, stream>>>(edge_src, edge_dst, mat_d, mat_s,
                                               h_user, use_h16 ? h16 : nullptr);

        // In-place flat exclusive scans of the count matrices.
        int nb_md = (MD_N + SCAN_ELEMS - 1) / SCAN_ELEMS;   // 59
        int nb_ms = (MS_N + SCAN_ELEMS - 1) / SCAN_ELEMS;   // 73
        scan1_kernel<<<nb_md, SCAN_BLOCK, 0, stream>>>(mat_d, mat_d, partial, MD_N);
        scan2_kernel<<<1, SCAN_BLOCK, 0, stream>>>(partial, nb_md, mat_d + MD_N);
        scan3_kernel<<<nb_md, SCAN_BLOCK, 0, stream>>>(mat_d, partial, MD_N);
        scan1_kernel<<<nb_ms, SCAN_BLOCK, 0, stream>>>(mat_s, mat_s, partial, MS_N);
        scan2_kernel<<<1, SCAN_BLOCK, 0, stream>>>(partial, nb_ms, mat_s + MS_N);
        scan3_kernel<<<nb_ms, SCAN_BLOCK, 0, stream>>>(mat_s, partial, MS_N);

        passA<<<GRID_A, BLK, 0, stream>>>(edge_src, edge_dst, mat_d, mat_s,
                                          coarse_dst, coarse_src);

        if (use_h16) {
            sortgather<KD_SHIFT, CAP_D, 8, false, unsigned short>
                <<<C_DST, 512, 0, stream>>>(coarse_dst, mat_d, h16, rst,
                                            use_r16 ? rp0 : nullptr,
                                            use_r16 ? rp1 : nullptr, N_GROUP);
        } else {
            sortgather<KD_SHIFT, CAP_D, 8, false, float>
                <<<C_DST, 512, 0, stream>>>(coarse_dst, mat_d, h_user, rst,
                                            use_r16 ? rp0 : nullptr,
                                            use_r16 ? rp1 : nullptr, N_GROUP);
        }
        if (use_r16) {
            sortgather_bwd<KS_SHIFT, CAP_S>
                <<<C_SRC, 512, 0, stream>>>(coarse_src, mat_s, rp0, rp1, bsrc, N_USER);
        } else {
            sortgather<KS_SHIFT, CAP_S, 4, true, float>
                <<<C_SRC, 512, 0, stream>>>(coarse_src, mat_s, rst, bsrc,
                                            nullptr, nullptr, N_USER);
        }
        return;
    }

    if (ws_size >= need_csr2) {
        // ---- fallback: hist+scan+fused fill (round-3 structure) ---------
        bool use_h16 = (ws_size >= need_full);
        bool use_r16 = (ws_size >= need_r16);

        hipMemsetAsync(d_ws, 0, (size_t)(partial - ws) * sizeof(int), stream);

        if (use_h16) {
            long n4 = (long)N_USER * DIM / 4;
            cvt_bf16<<<(int)((n4 + BLK - 1) / BLK), BLK, 0, stream>>>(h_user, h16, n4);
        }

        hist_kernel<<<grid_e, BLK, 0, stream>>>(edge_src, edge_dst, cnt_src, cnt_dst);

        scan1_kernel<<<nb_dst, SCAN_BLOCK, 0, stream>>>(cnt_dst, off_dst, partial, N_GROUP);
        scan2_kernel<<<1, SCAN_BLOCK, 0, stream>>>(partial, nb_dst, off_dst + N_GROUP);
        scan3_kernel<<<nb_dst, SCAN_BLOCK, 0, stream>>>(off_dst, partial, N_GROUP);

        scan1_kernel<<<nb_src, SCAN_BLOCK, 0, stream>>>(cnt_src, off_src, partial, N_USER);
        scan2_kernel<<<1, SCAN_BLOCK, 0, stream>>>(partial, nb_src, off_src + N_USER);
        scan3_kernel<<<nb_src, SCAN_BLOCK, 0, stream>>>(off_src, partial, N_USER);

        fill_both<<<grid_e, BLK, 0, stream>>>(
            edge_src, edge_dst, off_src, off_dst,
            cur_src, cur_dst, bucket_src, bucket_dst);

        unsigned short* r16p = use_r16 ? r16 : (unsigned short*)nullptr;
        if (use_h16) {
            gather_kernel<N_GROUP, false, 8, unsigned short>
                <<<(N_GROUP * 64 + BLK - 1) / BLK, BLK, 0, stream>>>(
                    off_dst, bucket_dst, h16, rst, r16p);
        } else {
            gather_kernel<N_GROUP, false, 8, float>
                <<<(N_GROUP * 64 + BLK - 1) / BLK, BLK, 0, stream>>>(
                    off_dst, bucket_dst, h_user, rst, r16p);
        }
        if (use_r16) {
            gather_kernel<N_USER, true, 4, unsigned short>
                <<<(int)(((size_t)N_USER * 64 + BLK - 1) / BLK), BLK, 0, stream>>>(
                    off_src, bucket_src, r16, bsrc, nullptr);
        } else {
            gather_kernel<N_USER, true, 4, float>
                <<<(int)(((size_t)N_USER * 64 + BLK - 1) / BLK), BLK, 0, stream>>>(
                    off_src, bucket_src, rst, bsrc, nullptr);
        }
        return;
    }

    if (ws_size >= need_csr1) {
        // Sequential single-bucket path (f32 gathers).
        hipMemsetAsync(d_ws, 0, (size_t)(partial - ws) * sizeof(int), stream);
        hist_kernel<<<grid_e, BLK, 0, stream>>>(edge_src, edge_dst, cnt_src, cnt_dst);

        scan1_kernel<<<nb_dst, SCAN_BLOCK, 0, stream>>>(cnt_dst, off_dst, partial, N_GROUP);
        scan2_kernel<<<1, SCAN_BLOCK, 0, stream>>>(partial, nb_dst, off_dst + N_GROUP);
        scan3_kernel<<<nb_dst, SCAN_BLOCK, 0, stream>>>(off_dst, partial, N_GROUP);

        scan1_kernel<<<nb_src, SCAN_BLOCK, 0, stream>>>(cnt_src, off_src, partial, N_USER);
        scan2_kernel<<<1, SCAN_BLOCK, 0, stream>>>(partial, nb_src, off_src + N_USER);
        scan3_kernel<<<nb_src, SCAN_BLOCK, 0, stream>>>(off_src, partial, N_USER);

        fill_one<<<grid_e, BLK, 0, stream>>>(edge_dst, edge_src, off_dst, cur_dst, bucket_dst);
        gather_kernel<N_GROUP, false, 8, float>
            <<<(N_GROUP * 64 + BLK - 1) / BLK, BLK, 0, stream>>>(
                off_dst, bucket_dst, h_user, rst, nullptr);

        fill_one<<<grid_e, BLK, 0, stream>>>(edge_src, edge_dst, off_src, cur_src, bucket_dst);
        gather_kernel<N_USER, true, 4, float>
            <<<(int)(((size_t)N_USER * 64 + BLK - 1) / BLK), BLK, 0, stream>>>(
                off_src, bucket_dst, rst, bsrc, nullptr);
        return;
    }

    // ---- Fallback: atomic path ------------------------------------------
    float* deg_dst = (float*)d_ws;
    float* deg_src = deg_dst + N_GROUP;
    hipMemsetAsync(d_out, 0, (size_t)(N_USER + N_GROUP) * DIM * sizeof(float), stream);
    hipMemsetAsync(d_ws, 0, (size_t)(N_USER + N_GROUP) * sizeof(float), stream);

    deg_kernel<<<grid_e, BLK, 0, stream>>>(edge_src, edge_dst, deg_src, deg_dst);

    long total_ed = (long)N_EDGE * DIM;
    int grid_ed = (int)((total_ed + BLK - 1) / BLK);
    scatter_fwd<<<grid_ed, BLK, 0, stream>>>(edge_src, edge_dst, h_user, rst);
    long total_g = (long)N_GROUP * DIM;
    norm_kernel<<<(int)((total_g + BLK - 1) / BLK), BLK, 0, stream>>>(rst, deg_dst, total_g);
    scatter_bwd<<<grid_ed, BLK, 0, stream>>>(edge_src, edge_dst, rst, bsrc);
    long total_u = (long)N_USER * DIM;
    norm_kernel<<<(int)((total_u + BLK - 1) / BLK), BLK, 0, stream>>>(bsrc, deg_src, total_u);
}

// Round 10
// 566.839 us; speedup vs baseline: 1.1195x; 1.1195x over previous
//
#include <hip/hip_runtime.h>

// Problem constants (match reference)
#define N_USER  500000
#define N_GROUP 100000
#define N_EDGE  5000000
#define DIM     64

#define SCAN_BLOCK 256
#define SCAN_ELEMS 4096            // elements per scan block (16 per thread)
#define PER_THREAD (SCAN_ELEMS / SCAN_BLOCK)

// Multisplit coarse-bucket geometry
#define KD_SHIFT 7                                   // 128 group-keys / coarse bucket
#define KS_SHIFT 9                                   // 512 user-keys / coarse bucket
#define C_DST ((N_GROUP + (1 << KD_SHIFT) - 1) >> KD_SHIFT)   // 782
#define C_SRC ((N_USER  + (1 << KS_SHIFT) - 1) >> KS_SHIFT)   // 977
#define TILE_A 16384                                 // edges per pass-A block
#define GRID_A ((N_EDGE + TILE_A - 1) / TILE_A)      // 306
#define CVT_BLOCKS 1024
// LDS staging caps: mean + ~16 sigma
#define CAP_D 7680
#define CAP_S 6272
// count-matrix sizes; combined scan over [mat_d | mat_s]
#define MD_N (C_DST * GRID_A)
#define MS_N (C_SRC * GRID_A)
#define MC_N (MD_N + MS_N)

typedef unsigned int uint32;

__device__ inline unsigned short f2bf(float x) {
    uint32 b = __float_as_uint(x);
    uint32 r = (b + 0x7FFFu + ((b >> 16) & 1u)) >> 16;   // round-to-nearest-even
    return (unsigned short)r;
}
__device__ inline float ldt(const float* t, size_t i) { return t[i]; }
__device__ inline float ldt(const unsigned short* t, size_t i) {
    return __uint_as_float((uint32)t[i] << 16);
}

// ---------------------------------------------------------------------------
// Fused prep: blocks [0,GRID_A) build their per-block coarse histogram in LDS
// and store it into the [bucket][block] count matrices (no global atomics);
// blocks [GRID_A, GRID_A+CVT_BLOCKS) convert h_user -> bf16.
// ---------------------------------------------------------------------------
__global__ void prep_kernel(const int* __restrict__ src,
                            const int* __restrict__ dst,
                            int* __restrict__ mat_d,
                            int* __restrict__ mat_s,
                            const float* __restrict__ hin,
                            unsigned short* __restrict__ h16) {
    __shared__ int hd[C_DST], hs[C_SRC];
    int tid = threadIdx.x;
    int b = blockIdx.x;
    if (b < GRID_A) {
        long base = (long)b * TILE_A;
        for (int k = tid; k < C_DST; k += blockDim.x) hd[k] = 0;
        for (int k = tid; k < C_SRC; k += blockDim.x) hs[k] = 0;
        __syncthreads();
        for (int i = tid; i < TILE_A; i += blockDim.x) {
            long e = base + i;
            if (e >= N_EDGE) break;
            atomicAdd(&hd[dst[e] >> KD_SHIFT], 1);
            atomicAdd(&hs[src[e] >> KS_SHIFT], 1);
        }
        __syncthreads();
        for (int k = tid; k < C_DST; k += blockDim.x) mat_d[(size_t)k * GRID_A + b] = hd[k];
        for (int k = tid; k < C_SRC; k += blockDim.x) mat_s[(size_t)k * GRID_A + b] = hs[k];
    } else if (h16) {
        long n4 = (long)N_USER * DIM / 4;
        long stride = (long)CVT_BLOCKS * blockDim.x;
        for (long i = (long)(b - GRID_A) * blockDim.x + tid; i < n4; i += stride) {
            const float4 v = ((const float4*)hin)[i];
            ushort4 o;
            o.x = f2bf(v.x); o.y = f2bf(v.y); o.z = f2bf(v.z); o.w = f2bf(v.w);
            ((ushort4*)h16)[i] = o;
        }
    }
}

// ---------------------------------------------------------------------------
// Exclusive scan (3 stages). Used in-place on the combined count matrix and
// by the fallback tiers.
// ---------------------------------------------------------------------------
__global__ void scan1_kernel(const int* __restrict__ cnt,
                             int* __restrict__ off,
                             int* __restrict__ partial,
                             int n) {
    __shared__ int sh[SCAN_BLOCK];
    int tid = threadIdx.x;
    int tbase = blockIdx.x * SCAN_ELEMS + tid * PER_THREAD;
    int local[PER_THREAD];
    int sum = 0;
#pragma unroll
    for (int i = 0; i < PER_THREAD; ++i) {
        int idx = tbase + i;
        int v = (idx < n) ? cnt[idx] : 0;
        local[i] = sum;
        sum += v;
    }
    sh[tid] = sum;
    __syncthreads();
    for (int o = 1; o < SCAN_BLOCK; o <<= 1) {
        int t = (tid >= o) ? sh[tid - o] : 0;
        __syncthreads();
        sh[tid] += t;
        __syncthreads();
    }
    int texc = sh[tid] - sum;
    int blockTotal = sh[SCAN_BLOCK - 1];
#pragma unroll
    for (int i = 0; i < PER_THREAD; ++i) {
        int idx = tbase + i;
        if (idx < n) off[idx] = local[i] + texc;
    }
    if (tid == 0) partial[blockIdx.x] = blockTotal;
}

__global__ void scan2_kernel(int* __restrict__ partial, int nb,
                             int* __restrict__ off_end) {
    __shared__ int sh[SCAN_BLOCK];
    int tid = threadIdx.x;
    int v = (tid < nb) ? partial[tid] : 0;
    sh[tid] = v;
    __syncthreads();
    for (int o = 1; o < SCAN_BLOCK; o <<= 1) {
        int t = (tid >= o) ? sh[tid - o] : 0;
        __syncthreads();
        sh[tid] += t;
        __syncthreads();
    }
    if (tid < nb) partial[tid] = sh[tid] - v;
    if (tid == 0) *off_end = sh[SCAN_BLOCK - 1];
}

__global__ void scan3_kernel(int* __restrict__ off,
                             const int* __restrict__ partial, int n) {
    int base = blockIdx.x * SCAN_ELEMS;
    int add = partial[blockIdx.x];
    for (int i = threadIdx.x; i < SCAN_ELEMS; i += blockDim.x) {
        int idx = base + i;
        if (idx < n) off[idx] += add;
    }
}

// ---------------------------------------------------------------------------
// Pass A: exact-offset placement into ONE combined coarse array. Each block
// loads its column of the scanned count matrices (absolute run bases), then
// places packed u32 (keylo<<20|val) with LDS cursor atomics only.
// ---------------------------------------------------------------------------
__global__ void passA(const int* __restrict__ src,
                      const int* __restrict__ dst,
                      const int* __restrict__ mat_d,
                      const int* __restrict__ mat_s,
                      uint32* __restrict__ coarse) {
    __shared__ int bd[C_DST], bs[C_SRC];
    int tid = threadIdx.x;
    int b = blockIdx.x;
    long base = (long)b * TILE_A;

    for (int c = tid; c < C_DST; c += blockDim.x) bd[c] = mat_d[(size_t)c * GRID_A + b];
    for (int c = tid; c < C_SRC; c += blockDim.x) bs[c] = mat_s[(size_t)c * GRID_A + b];
    __syncthreads();

    for (int i = tid; i < TILE_A; i += blockDim.x) {
        long e = base + i;
        if (e >= N_EDGE) break;
        int g = dst[e], u = src[e];
        int cd = g >> KD_SHIFT;
        int pd = atomicAdd(&bd[cd], 1);
        coarse[pd] = ((uint32)(g & ((1 << KD_SHIFT) - 1)) << 20) | (uint32)u;
        int cs = u >> KS_SHIFT;
        int ps = atomicAdd(&bs[cs], 1);
        coarse[ps] = ((uint32)(u & ((1 << KS_SHIFT) - 1)) << 20) | (uint32)g;
    }
}

// ---------------------------------------------------------------------------
// Fused sort+gather: one 512-thread block per coarse bucket. Builds the
// fine-sorted adjacency of its <=2^SHIFT keys in LDS (hist -> scan -> place),
// then 8 waves gather rows (per edge: one LDS broadcast + one coalesced
// full-row table load). beg/end from the scanned count matrix (stride GRID_A).
// out16 optionally emits a bf16 copy of the result row.
// ---------------------------------------------------------------------------
template <int SHIFT, int CAP, int U, bool NT, typename T>
__global__ __launch_bounds__(512) void sortgather(
    const uint32* __restrict__ coarse,
    const int* __restrict__ mat,
    const T* __restrict__ table,
    float* __restrict__ out,
    unsigned short* __restrict__ out16,
    int n) {
    const int NK = 1 << SHIFT;
    __shared__ int vals[CAP];
    __shared__ int hist[NK];
    __shared__ int cur[NK];
    int tid = threadIdx.x;
    int c = blockIdx.x;
    int lo_g = c << SHIFT;
    int beg = mat[(size_t)c * GRID_A];
    int end = mat[(size_t)(c + 1) * GRID_A];
    int cnt = end - beg;
    int stg = min(cnt, CAP);

    for (int k = tid; k < NK; k += 512) hist[k] = 0;
    __syncthreads();

    for (int i = tid; i < stg; i += 512) {
        atomicAdd(&hist[coarse[beg + i] >> 20], 1);
    }
    __syncthreads();

    for (int o = 1; o < NK; o <<= 1) {
        int t = (tid < NK && tid >= o) ? hist[tid - o] : 0;
        __syncthreads();
        if (tid < NK) hist[tid] += t;
        __syncthreads();
    }
    if (tid < NK) cur[tid] = (tid == 0) ? 0 : hist[tid - 1];
    __syncthreads();

    for (int i = tid; i < stg; i += 512) {
        uint32 kv = coarse[beg + i];
        int p = atomicAdd(&cur[kv >> 20], 1);
        vals[p] = (int)(kv & 0xFFFFFu);
    }
    __syncthreads();

    int wv = tid >> 6, lane = tid & 63;
    for (int r = wv; r < NK; r += 8) {
        int row = lo_g + r;
        if (row >= n) break;
        int lo = (r == 0) ? 0 : hist[r - 1];
        int hi = hist[r];
        float a[U];
#pragma unroll
        for (int j = 0; j < U; ++j) a[j] = 0.0f;
        int e = lo;
        for (; e + U <= hi; e += U) {
#pragma unroll
            for (int j = 0; j < U; ++j) {
                int s = vals[e + j];
                a[j] += ldt(table, (size_t)s * DIM + lane);
            }
        }
        for (; e < hi; ++e) {
            int s = vals[e];
            a[0] += ldt(table, (size_t)s * DIM + lane);
        }
        int deg = hi - lo;
        if (stg < cnt) {                 // overflow scan (rare)
            for (int i = beg + stg; i < end; ++i) {
                uint32 kv = coarse[i];
                if ((int)(kv >> 20) == r) {
                    a[0] += ldt(table, (size_t)(kv & 0xFFFFFu) * DIM + lane);
                    ++deg;
                }
            }
        }
        float acc = 0.0f;
#pragma unroll
        for (int j = 0; j < U; ++j) acc += a[j];
        float rv = acc / fmaxf((float)deg, 1.0f);
        size_t oidx = (size_t)row * DIM + lane;
        if (NT) __builtin_nontemporal_store(rv, &out[oidx]);
        else out[oidx] = rv;
        if (out16) out16[oidx] = f2bf(rv);
    }
}

// ---------------------------------------------------------------------------
// Fallback-tier kernels (unchanged behavior).
// ---------------------------------------------------------------------------
__global__ void hist_kernel(const int* __restrict__ src,
                            const int* __restrict__ dst,
                            int* __restrict__ cnt_src,
                            int* __restrict__ cnt_dst) {
    int e = blockIdx.x * blockDim.x + threadIdx.x;
    if (e < N_EDGE) {
        atomicAdd(&cnt_src[src[e]], 1);
        atomicAdd(&cnt_dst[dst[e]], 1);
    }
}

__global__ void fill_both(const int* __restrict__ src,
                          const int* __restrict__ dst,
                          const int* __restrict__ off_src,
                          const int* __restrict__ off_dst,
                          int* __restrict__ cur_src,
                          int* __restrict__ cur_dst,
                          int* __restrict__ bucket_src,
                          int* __restrict__ bucket_dst) {
    int e = blockIdx.x * blockDim.x + threadIdx.x;
    if (e < N_EDGE) {
        int u = src[e];
        int g = dst[e];
        int p = atomicAdd(&cur_src[u], 1);
        bucket_src[off_src[u] + p] = g;
        int q = atomicAdd(&cur_dst[g], 1);
        bucket_dst[off_dst[g] + q] = u;
    }
}

__global__ void fill_one(const int* __restrict__ key,
                         const int* __restrict__ val,
                         const int* __restrict__ off,
                         int* __restrict__ cur,
                         int* __restrict__ bucket) {
    int e = blockIdx.x * blockDim.x + threadIdx.x;
    if (e < N_EDGE) {
        int k = key[e];
        int p = atomicAdd(&cur[k], 1);
        bucket[off[k] + p] = val[e];
    }
}

__global__ void cvt_bf16(const float* __restrict__ in,
                         unsigned short* __restrict__ out, long n4) {
    long i = (long)blockIdx.x * blockDim.x + threadIdx.x;
    if (i >= n4) return;
    const float4 v = ((const float4*)in)[i];
    ushort4 o;
    o.x = f2bf(v.x); o.y = f2bf(v.y); o.z = f2bf(v.z); o.w = f2bf(v.w);
    ((ushort4*)out)[i] = o;
}

// Gather (fallback tiers): one wave per row, window load + shfl broadcast.
template <int NROW, bool NT, int U, typename T>
__global__ void gather_kernel(const int* __restrict__ off,
                              const int* __restrict__ bucket,
                              const T* __restrict__ table,
                              float* __restrict__ out,
                              unsigned short* __restrict__ out16) {
    int wid = (blockIdx.x * blockDim.x + threadIdx.x) >> 6;
    int lane = threadIdx.x & 63;
    if (wid >= NROW) return;
    int beg = off[wid], end = off[wid + 1];

    float a[U];
#pragma unroll
    for (int j = 0; j < U; ++j) a[j] = 0.0f;

    for (int b = beg; b < end; b += 64) {
        int navail = min(64, end - b);
        int sv = bucket[b + (lane < navail ? lane : 0)];
        int k = 0;
        for (; k + U <= navail; k += U) {
#pragma unroll
            for (int j = 0; j < U; ++j) {
                int s = __shfl(sv, k + j);
                a[j] += ldt(table, (size_t)s * DIM + lane);
            }
        }
        if (k < navail) {
#pragma unroll
            for (int j = 0; j < U; ++j) {
                int kk = k + j;
                int s = __shfl(sv, kk < navail ? kk : navail - 1);
                float w = (kk < navail) ? 1.0f : 0.0f;
                a[j] += w * ldt(table, (size_t)s * DIM + lane);
            }
        }
    }
    float acc = 0.0f;
#pragma unroll
    for (int j = 0; j < U; ++j) acc += a[j];
    float inv = 1.0f / fmaxf((float)(end - beg), 1.0f);
    float r = acc * inv;
    if (NT) {
        __builtin_nontemporal_store(r, &out[(size_t)wid * DIM + lane]);
    } else {
        out[(size_t)wid * DIM + lane] = r;
    }
    if (out16) out16[(size_t)wid * DIM + lane] = f2bf(r);
}

// ===========================================================================
// Last-resort fallback (atomic path).
// ===========================================================================
__global__ void deg_kernel(const int* __restrict__ src,
                           const int* __restrict__ dst,
                           float* __restrict__ deg_src,
                           float* __restrict__ deg_dst) {
    int e = blockIdx.x * blockDim.x + threadIdx.x;
    if (e < N_EDGE) {
        unsafeAtomicAdd(&deg_src[src[e]], 1.0f);
        unsafeAtomicAdd(&deg_dst[dst[e]], 1.0f);
    }
}

__global__ void scatter_fwd(const int* __restrict__ src,
                            const int* __restrict__ dst,
                            const float* __restrict__ h_user,
                            float* __restrict__ rst) {
    long idx = (long)blockIdx.x * blockDim.x + threadIdx.x;
    if (idx >= (long)N_EDGE * DIM) return;
    int e = (int)(idx >> 6), d = (int)(idx & 63);
    unsafeAtomicAdd(&rst[(long)dst[e] * DIM + d], h_user[(long)src[e] * DIM + d]);
}

__global__ void norm_kernel(float* __restrict__ x,
                            const float* __restrict__ deg, long total) {
    long idx = (long)blockIdx.x * blockDim.x + threadIdx.x;
    if (idx >= total) return;
    float dg = fmaxf(deg[idx >> 6], 1.0f);
    x[idx] *= (1.0f / dg);
}

__global__ void scatter_bwd(const int* __restrict__ src,
                            const int* __restrict__ dst,
                            const float* __restrict__ rst,
                            float* __restrict__ bsrc) {
    long idx = (long)blockIdx.x * blockDim.x + threadIdx.x;
    if (idx >= (long)N_EDGE * DIM) return;
    int e = (int)(idx >> 6), d = (int)(idx & 63);
    unsafeAtomicAdd(&bsrc[(long)src[e] * DIM + d], rst[(long)dst[e] * DIM + d]);
}

extern "C" void kernel_launch(void* const* d_in, const int* in_sizes, int n_in,
                              void* d_out, int out_size, void* d_ws, size_t ws_size,
                              hipStream_t stream) {
    const float* h_user   = (const float*)d_in[0];
    const int*   edge_src = (const int*)d_in[2];
    const int*   edge_dst = (const int*)d_in[3];

    float* bsrc = (float*)d_out;                   // [N_USER, DIM]
    float* rst  = bsrc + (size_t)N_USER * DIM;     // [N_GROUP, DIM]

    const int BLK = 256;
    const int grid_e = (N_EDGE + BLK - 1) / BLK;

    // ---- scratch layout (header kept fallback-compatible) ---------------
    int* ws      = (int*)d_ws;
    int* cnt_dst = ws;                              // N_GROUP        (fallback only)
    int* off_dst = cnt_dst + N_GROUP;               // N_GROUP + 1
    int* cnt_src = off_dst + N_GROUP + 1;           // N_USER         (fallback only)
    int* off_src = cnt_src + N_USER;                // N_USER + 1
    int* cur_dst = off_src + N_USER + 1;            // N_GROUP        (fallback only)
    int* cur_src = cur_dst + N_GROUP;               // N_USER         (fallback only)
    int* partial = cur_src + N_USER;                // 256
    int* bucket_dst = partial + 256;                // N_EDGE (fallback only)
    int* bucket_src = bucket_dst + N_EDGE;          // N_EDGE (fallback only)
    unsigned short* r16 = (unsigned short*)(bucket_src + N_EDGE);  // N_GROUP*DIM
    unsigned short* h16 = r16 + (size_t)N_GROUP * DIM;             // N_USER*DIM
    // multisplit extras (8B-aligned tail)
    size_t tail = ((size_t)((char*)(h16 + (size_t)N_USER * DIM) - (char*)d_ws) + 7) & ~(size_t)7;
    int* mat_d = (int*)((char*)d_ws + tail);        // MD_N  (combined matrix head)
    int* mat_s = mat_d + MD_N;                      // MS_N  (+1 sentinel after)
    size_t tail2 = ((size_t)((char*)(mat_s + MS_N + 1) - (char*)d_ws) + 7) & ~(size_t)7;
    uint32* coarse = (uint32*)((char*)d_ws + tail2);  // 2*N_EDGE u32 (both sides)

    size_t need_csr1 = (size_t)((bucket_dst + N_EDGE) - ws) * sizeof(int);
    size_t need_csr2 = (size_t)((bucket_src + N_EDGE) - ws) * sizeof(int);
    size_t need_r16  = need_csr2 + (size_t)N_GROUP * DIM * 2;
    size_t need_full = need_r16 + (size_t)N_USER * DIM * 2;
    size_t need_ms   = (size_t)((char*)(coarse + 2 * (size_t)N_EDGE) - (char*)d_ws);

    int nb_dst = (N_GROUP + SCAN_ELEMS - 1) / SCAN_ELEMS;
    int nb_src = (N_USER + SCAN_ELEMS - 1) / SCAN_ELEMS;

    if (ws_size >= need_ms) {
        // ---- multisplit + exact-offset + fused sortgather ----------------
        bool use_h16 = (ws_size >= need_full);
        bool use_r16 = (ws_size >= need_r16);

        int gridP = GRID_A + (use_h16 ? CVT_BLOCKS : 0);
        prep_kernel<<<gridP, BLK, 0, stream>>>(edge_src, edge_dst, mat_d, mat_s,
                                               h_user, use_h16 ? h16 : nullptr);

        // One in-place flat exclusive scan over the combined count matrix.
        // Src-side offsets come out absolute into `coarse` (dst counts sum
        // to N_EDGE, so mat_s runs land in [N_EDGE, 2*N_EDGE)).
        int nb_mc = (MC_N + SCAN_ELEMS - 1) / SCAN_ELEMS;
        scan1_kernel<<<nb_mc, SCAN_BLOCK, 0, stream>>>(mat_d, mat_d, partial, MC_N);
        scan2_kernel<<<1, SCAN_BLOCK, 0, stream>>>(partial, nb_mc, mat_d + MC_N);
        scan3_kernel<<<nb_mc, SCAN_BLOCK, 0, stream>>>(mat_d, partial, MC_N);

        passA<<<GRID_A, BLK, 0, stream>>>(edge_src, edge_dst, mat_d, mat_s, coarse);

        unsigned short* r16p = use_r16 ? r16 : (unsigned short*)nullptr;
        if (use_h16) {
            sortgather<KD_SHIFT, CAP_D, 8, false, unsigned short>
                <<<C_DST, 512, 0, stream>>>(coarse, mat_d, h16, rst, r16p, N_GROUP);
        } else {
            sortgather<KD_SHIFT, CAP_D, 8, false, float>
                <<<C_DST, 512, 0, stream>>>(coarse, mat_d, h_user, rst, r16p, N_GROUP);
        }
        if (use_r16) {
            sortgather<KS_SHIFT, CAP_S, 4, true, unsigned short>
                <<<C_SRC, 512, 0, stream>>>(coarse, mat_s, r16, bsrc, nullptr, N_USER);
        } else {
            sortgather<KS_SHIFT, CAP_S, 4, true, float>
                <<<C_SRC, 512, 0, stream>>>(coarse, mat_s, rst, bsrc, nullptr, N_USER);
        }
        return;
    }

    if (ws_size >= need_csr2) {
        // ---- fallback: hist+scan+fused fill (round-3 structure) ---------
        bool use_h16 = (ws_size >= need_full);
        bool use_r16 = (ws_size >= need_r16);

        hipMemsetAsync(d_ws, 0, (size_t)(partial - ws) * sizeof(int), stream);

        if (use_h16) {
            long n4 = (long)N_USER * DIM / 4;
            cvt_bf16<<<(int)((n4 + BLK - 1) / BLK), BLK, 0, stream>>>(h_user, h16, n4);
        }

        hist_kernel<<<grid_e, BLK, 0, stream>>>(edge_src, edge_dst, cnt_src, cnt_dst);

        scan1_kernel<<<nb_dst, SCAN_BLOCK, 0, stream>>>(cnt_dst, off_dst, partial, N_GROUP);
        scan2_kernel<<<1, SCAN_BLOCK, 0, stream>>>(partial, nb_dst, off_dst + N_GROUP);
        scan3_kernel<<<nb_dst, SCAN_BLOCK, 0, stream>>>(off_dst, partial, N_GROUP);

        scan1_kernel<<<nb_src, SCAN_BLOCK, 0, stream>>>(cnt_src, off_src, partial, N_USER);
        scan2_kernel<<<1, SCAN_BLOCK, 0, stream>>>(partial, nb_src, off_src + N_USER);
        scan3_kernel<<<nb_src, SCAN_BLOCK, 0, stream>>>(off_src, partial, N_USER);

        fill_both<<<grid_e, BLK, 0, stream>>>(
            edge_src, edge_dst, off_src, off_dst,
            cur_src, cur_dst, bucket_src, bucket_dst);

        unsigned short* r16p = use_r16 ? r16 : (unsigned short*)nullptr;
        if (use_h16) {
            gather_kernel<N_GROUP, false, 8, unsigned short>
                <<<(N_GROUP * 64 + BLK - 1) / BLK, BLK, 0, stream>>>(
                    off_dst, bucket_dst, h16, rst, r16p);
        } else {
            gather_kernel<N_GROUP, false, 8, float>
                <<<(N_GROUP * 64 + BLK - 1) / BLK, BLK, 0, stream>>>(
                    off_dst, bucket_dst, h_user, rst, r16p);
        }
        if (use_r16) {
            gather_kernel<N_USER, true, 4, unsigned short>
                <<<(int)(((size_t)N_USER * 64 + BLK - 1) / BLK), BLK, 0, stream>>>(
                    off_src, bucket_src, r16, bsrc, nullptr);
        } else {
            gather_kernel<N_USER, true, 4, float>
                <<<(int)(((size_t)N_USER * 64 + BLK - 1) / BLK), BLK, 0, stream>>>(
                    off_src, bucket_src, rst, bsrc, nullptr);
        }
        return;
    }

    if (ws_size >= need_csr1) {
        // Sequential single-bucket path (f32 gathers).
        hipMemsetAsync(d_ws, 0, (size_t)(partial - ws) * sizeof(int), stream);
        hist_kernel<<<grid_e, BLK, 0, stream>>>(edge_src, edge_dst, cnt_src, cnt_dst);

        scan1_kernel<<<nb_dst, SCAN_BLOCK, 0, stream>>>(cnt_dst, off_dst, partial, N_GROUP);
        scan2_kernel<<<1, SCAN_BLOCK, 0, stream>>>(partial, nb_dst, off_dst + N_GROUP);
        scan3_kernel<<<nb_dst, SCAN_BLOCK, 0, stream>>>(off_dst, partial, N_GROUP);

        scan1_kernel<<<nb_src, SCAN_BLOCK, 0, stream>>>(cnt_src, off_src, partial, N_USER);
        scan2_kernel<<<1, SCAN_BLOCK, 0, stream>>>(partial, nb_src, off_src + N_USER);
        scan3_kernel<<<nb_src, SCAN_BLOCK, 0, stream>>>(off_src, partial, N_USER);

        fill_one<<<grid_e, BLK, 0, stream>>>(edge_dst, edge_src, off_dst, cur_dst, bucket_dst);
        gather_kernel<N_GROUP, false, 8, float>
            <<<(N_GROUP * 64 + BLK - 1) / BLK, BLK, 0, stream>>>(
                off_dst, bucket_dst, h_user, rst, nullptr);

        fill_one<<<grid_e, BLK, 0, stream>>>(edge_src, edge_dst, off_src, cur_src, bucket_dst);
        gather_kernel<N_USER, true, 4, float>
            <<<(int)(((size_t)N_USER * 64 + BLK - 1) / BLK), BLK, 0, stream>>>(
                off_src, bucket_dst, rst, bsrc, nullptr);
        return;
    }

    // ---- Fallback: atomic path ------------------------------------------
    float* deg_dst = (float*)d_ws;
    float* deg_src = deg_dst + N_GROUP;
    hipMemsetAsync(d_out, 0, (size_t)(N_USER + N_GROUP) * DIM * sizeof(float), stream);
    hipMemsetAsync(d_ws, 0, (size_t)(N_USER + N_GROUP) * sizeof(float), stream);

    deg_kernel<<<grid_e, BLK, 0, stream>>>(edge_src, edge_dst, deg_src, deg_dst);

    long total_ed = (long)N_EDGE * DIM;
    int grid_ed = (int)((total_ed + BLK - 1) / BLK);
    scatter_fwd<<<grid_ed, BLK, 0, stream>>>(edge_src, edge_dst, h_user, rst);
    long total_g = (long)N_GROUP * DIM;
    norm_kernel<<<(int)((total_g + BLK - 1) / BLK), BLK, 0, stream>>>(rst, deg_dst, total_g);
    scatter_bwd<<<grid_ed, BLK, 0, stream>>>(edge_src, edge_dst, rst, bsrc);
    long total_u = (long)N_USER * DIM;
    norm_kernel<<<(int)((total_u + BLK - 1) / BLK), BLK, 0, stream>>>(bsrc, deg_src, total_u);
}